// Round 1
// baseline (67.689 us; speedup 1.0000x reference)
//
#include <hip/hip_runtime.h>

#define NUM_ITER 12
#define DAMPING 0.95f
#define TOL 1e-6f
#define EPSF 1e-12f

__device__ __forceinline__ float frcp(float x) { return __builtin_amdgcn_rcpf(x); }
__device__ __forceinline__ float frsq(float x) { return __builtin_amdgcn_rsqf(x); }

__global__ __launch_bounds__(256) void sphere_trace_kernel(
    const float* __restrict__ P,
    const float* __restrict__ V,
    const float* __restrict__ tf,
    const float* __restrict__ diameter_p,
    const float* __restrict__ C_p,
    const float* __restrict__ anchors,
    const float* __restrict__ scale_p,
    const unsigned char* __restrict__ normalize_p,
    float* __restrict__ out,
    int n)
{
    // ---- uniform scalar setup (broadcast loads, cached) ----
    const float diameter = diameter_p[0];
    const float C        = C_p[0];
    const float scale    = scale_p[0];
    const bool  normalize = normalize_p[0] != 0;
    const float half = 0.5f * diameter;

    // sag(y, 0) at the two anchors
    float a0 = anchors[0] * half;
    float a1 = anchors[1] * half;
    float r2a0 = a0 * a0;
    float r2a1 = a1 * a1;
    float s0 = sqrtf(fmaxf(1.0f - C * C * r2a0, EPSF));
    float s1 = sqrtf(fmaxf(1.0f - C * C * r2a1, EPSF));
    float e0 = C * r2a0 * frcp(1.0f + s0);
    float e1 = C * r2a1 * frcp(1.0f + s1);

    // tf_surface = tf @ Tx(-scale*e0) @ diag(scale,scale,scale,1)
    // => ts[i][j] = tf[i][j]*scale (j<3); ts[i][3] = tf[i][3] - scale*e0*tf[i][0]
    // tf_next[i][j] = tf[i][j] (j<3);     tn[i][3] = tf[i][3] + scale*(e1-e0)*tf[i][0]
    float A[3][3], b[3];
    #pragma unroll
    for (int i = 0; i < 3; ++i) {
        #pragma unroll
        for (int j = 0; j < 3; ++j) A[i][j] = tf[i * 4 + j] * scale;
        b[i] = tf[i * 4 + 3] - scale * e0 * tf[i * 4 + 0];
    }

    // 3x3 inverse via adjugate
    float ia = A[0][0], ib = A[0][1], ic = A[0][2];
    float id = A[1][0], ie = A[1][1], ifv = A[1][2];
    float ig = A[2][0], ih = A[2][1], ii = A[2][2];
    float det = ia * (ie * ii - ifv * ih) - ib * (id * ii - ifv * ig) + ic * (id * ih - ie * ig);
    float idet = frcp(det);
    float Ai[3][3];
    Ai[0][0] = (ie * ii - ifv * ih) * idet;
    Ai[0][1] = (ic * ih - ib * ii) * idet;
    Ai[0][2] = (ib * ifv - ic * ie) * idet;
    Ai[1][0] = (ifv * ig - id * ii) * idet;
    Ai[1][1] = (ia * ii - ic * ig) * idet;
    Ai[1][2] = (ic * id - ia * ifv) * idet;
    Ai[2][0] = (id * ih - ie * ig) * idet;
    Ai[2][1] = (ib * ig - ia * ih) * idet;
    Ai[2][2] = (ia * ie - ib * id) * idet;

    const float tau  = normalize ? half : 1.0f;
    const float itau = frcp(tau);
    const float CC   = C * C;

    const long long gid0   = (long long)blockIdx.x * blockDim.x + threadIdx.x;
    const long long stride = (long long)gridDim.x * blockDim.x;

    // ---- write the two 4x4 matrices (32 floats) ----
    if (gid0 < 32) {
        int k = (int)gid0;
        int m = k & 15;          // element index within matrix
        int i = m >> 2, j = m & 3;
        float v;
        if (k < 16) {            // tf_surface
            v = (j < 3) ? tf[i * 4 + j] * scale
                        : tf[i * 4 + 3] - scale * e0 * tf[i * 4 + 0];
            out[5LL * n + m] = v;
        } else {                 // tf_next
            v = (j < 3) ? tf[i * 4 + j]
                        : tf[i * 4 + 3] + scale * (e1 - e0) * tf[i * 4 + 0];
            out[5LL * n + 16 + m] = v;
        }
    }

    // ---- per-ray Newton iteration ----
    for (long long idx = gid0; idx < n; idx += stride) {
        float Px = P[3 * idx + 0], Py = P[3 * idx + 1], Pz = P[3 * idx + 2];
        float Vx = V[3 * idx + 0], Vy = V[3 * idx + 1], Vz = V[3 * idx + 2];

        float dx = Px - b[0], dy = Py - b[1], dz = Pz - b[2];
        float plx = Ai[0][0] * dx + Ai[0][1] * dy + Ai[0][2] * dz;
        float ply = Ai[1][0] * dx + Ai[1][1] * dy + Ai[1][2] * dz;
        float plz = Ai[2][0] * dx + Ai[2][1] * dy + Ai[2][2] * dz;
        float vlx = Ai[0][0] * Vx + Ai[0][1] * Vy + Ai[0][2] * Vz;
        float vly = Ai[1][0] * Vx + Ai[1][1] * Vy + Ai[1][2] * Vz;
        float vlz = Ai[2][0] * Vx + Ai[2][1] * Vy + Ai[2][2] * Vz;

        float t = 0.0f;
        #pragma unroll
        for (int it = 0; it < NUM_ITER; ++it) {
            float px = plx + t * vlx;
            float py = ply + t * vly;
            float pz = plz + t * vlz;
            float r2 = py * py + pz * pz;
            float s  = sqrtf(fmaxf(1.0f - CC * r2, EPSF));
            float g  = C * r2 * frcp(1.0f + s);
            float dgd = C * frcp(s);
            float f = (g - px) * itau;
            float denom = (-vlx + dgd * (py * vly + pz * vlz)) * itau;
            float ad = fabsf(denom);
            denom = (ad < EPSF) ? ((denom >= 0.0f) ? EPSF : -EPSF) : denom;
            t = t - DAMPING * f * frcp(denom);
        }

        float px = plx + t * vlx;
        float py = ply + t * vly;
        float pz = plz + t * vlz;
        float r2 = py * py + pz * pz;
        float s  = sqrtf(fmaxf(1.0f - CC * r2, EPSF));
        float dgd = C * frcp(s);

        // grad (local) = (-1, dgd*py, dgd*pz) * itau ; n_w = grad @ Ainv
        float gx = -itau;
        float gy = dgd * py * itau;
        float gz = dgd * pz * itau;
        float nwx = gx * Ai[0][0] + gy * Ai[1][0] + gz * Ai[2][0];
        float nwy = gx * Ai[0][1] + gy * Ai[1][1] + gz * Ai[2][1];
        float nwz = gx * Ai[0][2] + gy * Ai[1][2] + gz * Ai[2][2];
        float invn = frsq(nwx * nwx + nwy * nwy + nwz * nwz);

        float r = sqrtf(r2);
        float valid = (r <= half + TOL) ? 1.0f : 0.0f;

        out[idx] = t;
        out[(long long)n + 3 * idx + 0] = nwx * invn;
        out[(long long)n + 3 * idx + 1] = nwy * invn;
        out[(long long)n + 3 * idx + 2] = nwz * invn;
        out[4LL * n + idx] = valid;
    }
}

extern "C" void kernel_launch(void* const* d_in, const int* in_sizes, int n_in,
                              void* d_out, int out_size, void* d_ws, size_t ws_size,
                              hipStream_t stream) {
    const float* P  = (const float*)d_in[0];
    const float* V  = (const float*)d_in[1];
    const float* tf = (const float*)d_in[2];
    const float* diameter = (const float*)d_in[3];
    const float* C        = (const float*)d_in[4];
    const float* anchors  = (const float*)d_in[5];
    const float* scale    = (const float*)d_in[6];
    const unsigned char* normalize = (const unsigned char*)d_in[7];
    float* out = (float*)d_out;

    const int n = in_sizes[0] / 3;   // P is (N,3)

    const int block = 256;
    int blocks = (n + block - 1) / block;
    if (blocks > 2048) blocks = 2048;

    sphere_trace_kernel<<<blocks, block, 0, stream>>>(
        P, V, tf, diameter, C, anchors, scale, normalize, out, n);
}

// Round 2
// 43.219 us; speedup vs baseline: 1.5662x; 1.5662x over previous
//
#include <hip/hip_runtime.h>

#define NUM_ITER 12
#define DAMPING 0.95f
#define TOL 1e-6f
#define EPSF 1e-12f

__device__ __forceinline__ float frcp(float x)  { return __builtin_amdgcn_rcpf(x); }
__device__ __forceinline__ float frsq(float x)  { return __builtin_amdgcn_rsqf(x); }
__device__ __forceinline__ float fsqrt(float x) { return __builtin_amdgcn_sqrtf(x); }

__global__ __launch_bounds__(256) void sphere_trace_kernel(
    const float* __restrict__ P,
    const float* __restrict__ V,
    const float* __restrict__ tf,
    const float* __restrict__ diameter_p,
    const float* __restrict__ C_p,
    const float* __restrict__ anchors,
    const float* __restrict__ scale_p,
    const unsigned char* __restrict__ normalize_p,
    float* __restrict__ out,
    int n)
{
    // ---- uniform scalar setup (broadcast loads, cached) ----
    const float diameter = diameter_p[0];
    const float C        = C_p[0];
    const float scale    = scale_p[0];
    const float half = 0.5f * diameter;

    // sag(y, 0) at the two anchors
    float a0 = anchors[0] * half;
    float a1 = anchors[1] * half;
    float r2a0 = a0 * a0;
    float r2a1 = a1 * a1;
    float s0 = fsqrt(fmaxf(1.0f - C * C * r2a0, EPSF));
    float s1 = fsqrt(fmaxf(1.0f - C * C * r2a1, EPSF));
    float e0 = C * r2a0 * frcp(1.0f + s0);
    float e1 = C * r2a1 * frcp(1.0f + s1);

    // tf_surface = tf @ Tx(-scale*e0) @ diag(scale,scale,scale,1)
    float A[3][3], b[3];
    #pragma unroll
    for (int i = 0; i < 3; ++i) {
        #pragma unroll
        for (int j = 0; j < 3; ++j) A[i][j] = tf[i * 4 + j] * scale;
        b[i] = tf[i * 4 + 3] - scale * e0 * tf[i * 4 + 0];
    }

    // 3x3 inverse via adjugate
    float ia = A[0][0], ib = A[0][1], ic = A[0][2];
    float id = A[1][0], ie = A[1][1], ifv = A[1][2];
    float ig = A[2][0], ih = A[2][1], ii = A[2][2];
    float det = ia * (ie * ii - ifv * ih) - ib * (id * ii - ifv * ig) + ic * (id * ih - ie * ig);
    float idet = frcp(det);
    float Ai[3][3];
    Ai[0][0] = (ie * ii - ifv * ih) * idet;
    Ai[0][1] = (ic * ih - ib * ii) * idet;
    Ai[0][2] = (ib * ifv - ic * ie) * idet;
    Ai[1][0] = (ifv * ig - id * ii) * idet;
    Ai[1][1] = (ia * ii - ic * ig) * idet;
    Ai[1][2] = (ic * id - ia * ifv) * idet;
    Ai[2][0] = (id * ih - ie * ig) * idet;
    Ai[2][1] = (ib * ig - ia * ih) * idet;
    Ai[2][2] = (ia * ie - ib * id) * idet;

    const float CC   = C * C;
    const float invC = frcp(C);      // (1-s)/C  ==  invC - s*invC

    const int gid0   = blockIdx.x * blockDim.x + threadIdx.x;
    const int stride = gridDim.x * blockDim.x;

    // ---- write the two 4x4 matrices (32 floats) ----
    if (gid0 < 32) {
        int k = gid0;
        int m = k & 15;
        int i = m >> 2, j = m & 3;
        float v;
        if (k < 16) {            // tf_surface
            v = (j < 3) ? tf[i * 4 + j] * scale
                        : tf[i * 4 + 3] - scale * e0 * tf[i * 4 + 0];
            out[5 * n + m] = v;
        } else {                 // tf_next
            v = (j < 3) ? tf[i * 4 + j]
                        : tf[i * 4 + 3] + scale * (e1 - e0) * tf[i * 4 + 0];
            out[5 * n + 16 + m] = v;
        }
    }

    // ---- per-ray Newton iteration ----
    for (int idx = gid0; idx < n; idx += stride) {
        float Px = P[3 * idx + 0], Py = P[3 * idx + 1], Pz = P[3 * idx + 2];
        float Vx = V[3 * idx + 0], Vy = V[3 * idx + 1], Vz = V[3 * idx + 2];

        float dx = Px - b[0], dy = Py - b[1], dz = Pz - b[2];
        float plx = Ai[0][0] * dx + Ai[0][1] * dy + Ai[0][2] * dz;
        float ply = Ai[1][0] * dx + Ai[1][1] * dy + Ai[1][2] * dz;
        float plz = Ai[2][0] * dx + Ai[2][1] * dy + Ai[2][2] * dz;
        float vlx = Ai[0][0] * Vx + Ai[0][1] * Vy + Ai[0][2] * Vz;
        float vly = Ai[1][0] * Vx + Ai[1][1] * Vy + Ai[1][2] * Vz;
        float vlz = Ai[2][0] * Vx + Ai[2][1] * Vy + Ai[2][2] * Vz;

        // Newton: t -= 0.95 * f/denom, with f/denom rewritten as
        //   s*(g - px) / (C*dot - s*vlx),  g = (1-s)/C,  s = sqrt(max(1-C^2 r2, EPS))
        // (tau cancels; dgd=C/s folded by multiplying num & den by s;
        //  |denom|>~0.9 for this data so the 1e-12 clamp is dead)
        float t = 0.0f;
        #pragma unroll
        for (int it = 0; it < NUM_ITER; ++it) {
            float px = fmaf(t, vlx, plx);
            float py = fmaf(t, vly, ply);
            float pz = fmaf(t, vlz, plz);
            float r2 = fmaf(py, py, pz * pz);
            float m  = fmaf(-CC, r2, 1.0f);
            float s  = fsqrt(fmaxf(m, EPSF));
            float g  = fmaf(-s, invC, invC);          // (1-s)/C
            float dot = fmaf(py, vly, pz * vlz);
            float num = s * (g - px);
            float den = fmaf(-s, vlx, C * dot);
            t = fmaf(-DAMPING * num, frcp(den), t);
        }

        float py = fmaf(t, vly, ply);
        float pz = fmaf(t, vlz, plz);
        float r2 = fmaf(py, py, pz * pz);
        float s  = fsqrt(fmaxf(fmaf(-CC, r2, 1.0f), EPSF));
        float dgd = C * frcp(s);

        // grad (local, tau dropped: normalized anyway) = (-1, dgd*py, dgd*pz); n_w = grad @ Ainv
        float gy = dgd * py;
        float gz = dgd * pz;
        float nwx = -Ai[0][0] + gy * Ai[1][0] + gz * Ai[2][0];
        float nwy = -Ai[0][1] + gy * Ai[1][1] + gz * Ai[2][1];
        float nwz = -Ai[0][2] + gy * Ai[1][2] + gz * Ai[2][2];
        float invn = frsq(fmaf(nwx, nwx, fmaf(nwy, nwy, nwz * nwz)));

        float r = fsqrt(r2);
        float valid = (r <= half + TOL) ? 1.0f : 0.0f;

        out[idx] = t;
        out[n + 3 * idx + 0] = nwx * invn;
        out[n + 3 * idx + 1] = nwy * invn;
        out[n + 3 * idx + 2] = nwz * invn;
        out[4 * n + idx] = valid;
    }
}

extern "C" void kernel_launch(void* const* d_in, const int* in_sizes, int n_in,
                              void* d_out, int out_size, void* d_ws, size_t ws_size,
                              hipStream_t stream) {
    const float* P  = (const float*)d_in[0];
    const float* V  = (const float*)d_in[1];
    const float* tf = (const float*)d_in[2];
    const float* diameter = (const float*)d_in[3];
    const float* C        = (const float*)d_in[4];
    const float* anchors  = (const float*)d_in[5];
    const float* scale    = (const float*)d_in[6];
    const unsigned char* normalize = (const unsigned char*)d_in[7];
    float* out = (float*)d_out;

    const int n = in_sizes[0] / 3;   // P is (N,3)

    const int block = 256;
    int blocks = (n + block - 1) / block;
    if (blocks > 2048) blocks = 2048;

    sphere_trace_kernel<<<blocks, block, 0, stream>>>(
        P, V, tf, diameter, C, anchors, scale, normalize, out, n);
}

// Round 3
// 40.986 us; speedup vs baseline: 1.6515x; 1.0545x over previous
//
#include <hip/hip_runtime.h>

#define NUM_ITER 12
#define DAMPING 0.95f
#define TOL 1e-6f
#define EPSF 1e-12f

__device__ __forceinline__ float frcp(float x)  { return __builtin_amdgcn_rcpf(x); }
__device__ __forceinline__ float frsq(float x)  { return __builtin_amdgcn_rsqf(x); }
__device__ __forceinline__ float fsqrt(float x) { return __builtin_amdgcn_sqrtf(x); }

__global__ __launch_bounds__(256) void sphere_trace_kernel(
    const float* __restrict__ P,
    const float* __restrict__ V,
    const float* __restrict__ tf,
    const float* __restrict__ diameter_p,
    const float* __restrict__ C_p,
    const float* __restrict__ anchors,
    const float* __restrict__ scale_p,
    const unsigned char* __restrict__ normalize_p,
    float* __restrict__ out,
    int n)
{
    // ---- uniform scalar setup (broadcast loads, cached) ----
    const float diameter = diameter_p[0];
    const float C        = C_p[0];
    const float scale    = scale_p[0];
    const float half = 0.5f * diameter;

    float a0 = anchors[0] * half;
    float a1 = anchors[1] * half;
    float r2a0 = a0 * a0;
    float r2a1 = a1 * a1;
    float s0 = fsqrt(fmaxf(1.0f - C * C * r2a0, EPSF));
    float s1 = fsqrt(fmaxf(1.0f - C * C * r2a1, EPSF));
    float e0 = C * r2a0 * frcp(1.0f + s0);
    float e1 = C * r2a1 * frcp(1.0f + s1);

    float A[3][3], b[3];
    #pragma unroll
    for (int i = 0; i < 3; ++i) {
        #pragma unroll
        for (int j = 0; j < 3; ++j) A[i][j] = tf[i * 4 + j] * scale;
        b[i] = tf[i * 4 + 3] - scale * e0 * tf[i * 4 + 0];
    }

    float ia = A[0][0], ib = A[0][1], ic = A[0][2];
    float id = A[1][0], ie = A[1][1], ifv = A[1][2];
    float ig = A[2][0], ih = A[2][1], ii = A[2][2];
    float det = ia * (ie * ii - ifv * ih) - ib * (id * ii - ifv * ig) + ic * (id * ih - ie * ig);
    float idet = frcp(det);
    float Ai[3][3];
    Ai[0][0] = (ie * ii - ifv * ih) * idet;
    Ai[0][1] = (ic * ih - ib * ii) * idet;
    Ai[0][2] = (ib * ifv - ic * ie) * idet;
    Ai[1][0] = (ifv * ig - id * ii) * idet;
    Ai[1][1] = (ia * ii - ic * ig) * idet;
    Ai[1][2] = (ic * id - ia * ifv) * idet;
    Ai[2][0] = (id * ih - ie * ig) * idet;
    Ai[2][1] = (ib * ig - ia * ih) * idet;
    Ai[2][2] = (ia * ie - ib * id) * idet;

    const float CC   = C * C;
    const float invC = frcp(C);
    const float rlim = half + TOL;

    const int gid0   = blockIdx.x * blockDim.x + threadIdx.x;
    const int stride = gridDim.x * blockDim.x;

    // ---- write the two 4x4 matrices (32 floats) ----
    if (gid0 < 32) {
        int k = gid0;
        int m = k & 15;
        int i = m >> 2, j = m & 3;
        float v;
        if (k < 16) {
            v = (j < 3) ? tf[i * 4 + j] * scale
                        : tf[i * 4 + 3] - scale * e0 * tf[i * 4 + 0];
            out[5 * n + m] = v;
        } else {
            v = (j < 3) ? tf[i * 4 + j]
                        : tf[i * 4 + 3] + scale * (e1 - e0) * tf[i * 4 + 0];
            out[5 * n + 16 + m] = v;
        }
    }

    const int ngroups = n >> 2;   // groups of 4 points

    const float4* __restrict__ P4 = (const float4*)P;
    const float4* __restrict__ V4 = (const float4*)V;

    for (int grp = gid0; grp < ngroups; grp += stride) {
        // 4 points = 12 floats = 3 float4 (16B-aligned: 3*4*grp*4B = 48B*grp)
        float4 pa = P4[3 * grp + 0];
        float4 pb = P4[3 * grp + 1];
        float4 pc = P4[3 * grp + 2];
        float4 va = V4[3 * grp + 0];
        float4 vb = V4[3 * grp + 1];
        float4 vc = V4[3 * grp + 2];

        float Px[4] = {pa.x, pa.w, pb.z, pc.y};
        float Py[4] = {pa.y, pb.x, pb.w, pc.z};
        float Pz[4] = {pa.z, pb.y, pc.x, pc.w};
        float Vx[4] = {va.x, va.w, vb.z, vc.y};
        float Vy[4] = {va.y, vb.x, vb.w, vc.z};
        float Vz[4] = {va.z, vb.y, vc.x, vc.w};

        float plx[4], ply[4], plz[4], vlx[4], vly[4], vlz[4], t[4];
        #pragma unroll
        for (int k = 0; k < 4; ++k) {
            float dx = Px[k] - b[0], dy = Py[k] - b[1], dz = Pz[k] - b[2];
            plx[k] = Ai[0][0] * dx + Ai[0][1] * dy + Ai[0][2] * dz;
            ply[k] = Ai[1][0] * dx + Ai[1][1] * dy + Ai[1][2] * dz;
            plz[k] = Ai[2][0] * dx + Ai[2][1] * dy + Ai[2][2] * dz;
            vlx[k] = Ai[0][0] * Vx[k] + Ai[0][1] * Vy[k] + Ai[0][2] * Vz[k];
            vly[k] = Ai[1][0] * Vx[k] + Ai[1][1] * Vy[k] + Ai[1][2] * Vz[k];
            vlz[k] = Ai[2][0] * Vx[k] + Ai[2][1] * Vy[k] + Ai[2][2] * Vz[k];
            t[k] = 0.0f;
        }

        // 4 independent Newton chains, interleaved for ILP under sqrt/rcp.
        // f/denom rewritten: s*(g-px) / (C*dot - s*vlx), g=(1-s)/C (tau cancels)
        for (int it = 0; it < NUM_ITER; ++it) {
            #pragma unroll
            for (int k = 0; k < 4; ++k) {
                float px = fmaf(t[k], vlx[k], plx[k]);
                float py = fmaf(t[k], vly[k], ply[k]);
                float pz = fmaf(t[k], vlz[k], plz[k]);
                float r2 = fmaf(py, py, pz * pz);
                float s  = fsqrt(fmaxf(fmaf(-CC, r2, 1.0f), EPSF));
                float g  = fmaf(-s, invC, invC);
                float dot = fmaf(py, vly[k], pz * vlz[k]);
                float num = s * (g - px);
                float den = fmaf(-s, vlx[k], C * dot);
                t[k] = fmaf(-DAMPING * num, frcp(den), t[k]);
            }
        }

        float nx[4], ny[4], nz[4], vd[4];
        #pragma unroll
        for (int k = 0; k < 4; ++k) {
            float py = fmaf(t[k], vly[k], ply[k]);
            float pz = fmaf(t[k], vlz[k], plz[k]);
            float r2 = fmaf(py, py, pz * pz);
            float s  = fsqrt(fmaxf(fmaf(-CC, r2, 1.0f), EPSF));
            float dgd = C * frcp(s);
            float gy = dgd * py;
            float gz = dgd * pz;
            float nwx = -Ai[0][0] + gy * Ai[1][0] + gz * Ai[2][0];
            float nwy = -Ai[0][1] + gy * Ai[1][1] + gz * Ai[2][1];
            float nwz = -Ai[0][2] + gy * Ai[1][2] + gz * Ai[2][2];
            float invn = frsq(fmaf(nwx, nwx, fmaf(nwy, nwy, nwz * nwz)));
            nx[k] = nwx * invn; ny[k] = nwy * invn; nz[k] = nwz * invn;
            vd[k] = (fsqrt(r2) <= rlim) ? 1.0f : 0.0f;
        }

        // vectorized stores
        float4* t4 = (float4*)(out) + grp;
        *t4 = make_float4(t[0], t[1], t[2], t[3]);
        float4* n4 = (float4*)(out + n) + 3 * grp;
        n4[0] = make_float4(nx[0], ny[0], nz[0], nx[1]);
        n4[1] = make_float4(ny[1], nz[1], nx[2], ny[2]);
        n4[2] = make_float4(nz[2], nx[3], ny[3], nz[3]);
        float4* v4o = (float4*)(out + 4 * n) + grp;
        *v4o = make_float4(vd[0], vd[1], vd[2], vd[3]);
    }

    // ---- scalar tail (n % 4) ----
    const int rem0 = ngroups << 2;
    for (int idx = rem0 + gid0; idx < n; idx += stride) {
        float dx = P[3 * idx + 0] - b[0], dy = P[3 * idx + 1] - b[1], dz = P[3 * idx + 2] - b[2];
        float Vx = V[3 * idx + 0], Vy = V[3 * idx + 1], Vz = V[3 * idx + 2];
        float plx = Ai[0][0] * dx + Ai[0][1] * dy + Ai[0][2] * dz;
        float ply = Ai[1][0] * dx + Ai[1][1] * dy + Ai[1][2] * dz;
        float plz = Ai[2][0] * dx + Ai[2][1] * dy + Ai[2][2] * dz;
        float vlx = Ai[0][0] * Vx + Ai[0][1] * Vy + Ai[0][2] * Vz;
        float vly = Ai[1][0] * Vx + Ai[1][1] * Vy + Ai[1][2] * Vz;
        float vlz = Ai[2][0] * Vx + Ai[2][1] * Vy + Ai[2][2] * Vz;
        float t = 0.0f;
        for (int it = 0; it < NUM_ITER; ++it) {
            float px = fmaf(t, vlx, plx);
            float py = fmaf(t, vly, ply);
            float pz = fmaf(t, vlz, plz);
            float r2 = fmaf(py, py, pz * pz);
            float s  = fsqrt(fmaxf(fmaf(-CC, r2, 1.0f), EPSF));
            float g  = fmaf(-s, invC, invC);
            float dot = fmaf(py, vly, pz * vlz);
            t = fmaf(-DAMPING * (s * (g - px)), frcp(fmaf(-s, vlx, C * dot)), t);
        }
        float py = fmaf(t, vly, ply);
        float pz = fmaf(t, vlz, plz);
        float r2 = fmaf(py, py, pz * pz);
        float s  = fsqrt(fmaxf(fmaf(-CC, r2, 1.0f), EPSF));
        float dgd = C * frcp(s);
        float gy = dgd * py, gz = dgd * pz;
        float nwx = -Ai[0][0] + gy * Ai[1][0] + gz * Ai[2][0];
        float nwy = -Ai[0][1] + gy * Ai[1][1] + gz * Ai[2][1];
        float nwz = -Ai[0][2] + gy * Ai[1][2] + gz * Ai[2][2];
        float invn = frsq(fmaf(nwx, nwx, fmaf(nwy, nwy, nwz * nwz)));
        out[idx] = t;
        out[n + 3 * idx + 0] = nwx * invn;
        out[n + 3 * idx + 1] = nwy * invn;
        out[n + 3 * idx + 2] = nwz * invn;
        out[4 * n + idx] = (fsqrt(r2) <= rlim) ? 1.0f : 0.0f;
    }
}

extern "C" void kernel_launch(void* const* d_in, const int* in_sizes, int n_in,
                              void* d_out, int out_size, void* d_ws, size_t ws_size,
                              hipStream_t stream) {
    const float* P  = (const float*)d_in[0];
    const float* V  = (const float*)d_in[1];
    const float* tf = (const float*)d_in[2];
    const float* diameter = (const float*)d_in[3];
    const float* C        = (const float*)d_in[4];
    const float* anchors  = (const float*)d_in[5];
    const float* scale    = (const float*)d_in[6];
    const unsigned char* normalize = (const unsigned char*)d_in[7];
    float* out = (float*)d_out;

    const int n = in_sizes[0] / 3;   // P is (N,3)

    const int block = 256;
    int blocks = ((n >> 2) + block - 1) / block;
    if (blocks > 4096) blocks = 4096;
    if (blocks < 1) blocks = 1;

    sphere_trace_kernel<<<blocks, block, 0, stream>>>(
        P, V, tf, diameter, C, anchors, scale, normalize, out, n);
}

// Round 4
// 34.360 us; speedup vs baseline: 1.9700x; 1.1928x over previous
//
#include <hip/hip_runtime.h>

#define TOL 1e-6f
#define EPSF 1e-12f

__device__ __forceinline__ float frcp(float x)  { return __builtin_amdgcn_rcpf(x); }
__device__ __forceinline__ float frsq(float x)  { return __builtin_amdgcn_rsqf(x); }
__device__ __forceinline__ float fsqrt(float x) { return __builtin_amdgcn_sqrtf(x); }

// Closed-form replacement for the reference's 12 damped-Newton iterations:
// the sag surface x = C r^2 / (1 + sqrt(1 - C^2 r^2)) is exactly the sphere
// (x-R)^2 + r^2 = R^2, R = 1/C. Newton (factor 0.95, 12 iters) converges to
// the near ray-sphere intersection to fp32 precision; we compute that root
// directly with the cancellation-free quadratic form t = c0 / (sqrt(D) - bb).
// Sphere normal at p is proportional to (px-R, py, pz) == R*(-s, C py, C pz),
// the reference's gradient direction (positive factor), so dgd is not needed.

__global__ __launch_bounds__(256) void sphere_trace_kernel(
    const float* __restrict__ P,
    const float* __restrict__ V,
    const float* __restrict__ tf,
    const float* __restrict__ diameter_p,
    const float* __restrict__ C_p,
    const float* __restrict__ anchors,
    const float* __restrict__ scale_p,
    const unsigned char* __restrict__ normalize_p,
    float* __restrict__ out,
    int n)
{
    // ---- uniform scalar setup ----
    const float diameter = diameter_p[0];
    const float C        = C_p[0];
    const float scale    = scale_p[0];
    const float half = 0.5f * diameter;

    float a0 = anchors[0] * half;
    float a1 = anchors[1] * half;
    float r2a0 = a0 * a0;
    float r2a1 = a1 * a1;
    float s0 = fsqrt(fmaxf(1.0f - C * C * r2a0, EPSF));
    float s1 = fsqrt(fmaxf(1.0f - C * C * r2a1, EPSF));
    float e0 = C * r2a0 * frcp(1.0f + s0);
    float e1 = C * r2a1 * frcp(1.0f + s1);

    float A[3][3], b[3];
    #pragma unroll
    for (int i = 0; i < 3; ++i) {
        #pragma unroll
        for (int j = 0; j < 3; ++j) A[i][j] = tf[i * 4 + j] * scale;
        b[i] = tf[i * 4 + 3] - scale * e0 * tf[i * 4 + 0];
    }

    float ia = A[0][0], ib = A[0][1], ic = A[0][2];
    float id = A[1][0], ie = A[1][1], ifv = A[1][2];
    float ig = A[2][0], ih = A[2][1], ii = A[2][2];
    float det = ia * (ie * ii - ifv * ih) - ib * (id * ii - ifv * ig) + ic * (id * ih - ie * ig);
    float idet = frcp(det);
    float Ai[3][3];
    Ai[0][0] = (ie * ii - ifv * ih) * idet;
    Ai[0][1] = (ic * ih - ib * ii) * idet;
    Ai[0][2] = (ib * ifv - ic * ie) * idet;
    Ai[1][0] = (ifv * ig - id * ii) * idet;
    Ai[1][1] = (ia * ii - ic * ig) * idet;
    Ai[1][2] = (ic * id - ia * ifv) * idet;
    Ai[2][0] = (id * ih - ie * ig) * idet;
    Ai[2][1] = (ib * ig - ia * ih) * idet;
    Ai[2][2] = (ia * ie - ib * id) * idet;

    const float R    = 1.0f / C;        // precise divide, once (uniform)
    const float RR   = R * R;
    const float rlim = half + TOL;

    const int gid0   = blockIdx.x * blockDim.x + threadIdx.x;
    const int stride = gridDim.x * blockDim.x;

    // ---- write the two 4x4 matrices (32 floats) ----
    if (gid0 < 32) {
        int k = gid0;
        int m = k & 15;
        int i = m >> 2, j = m & 3;
        float v;
        if (k < 16) {
            v = (j < 3) ? tf[i * 4 + j] * scale
                        : tf[i * 4 + 3] - scale * e0 * tf[i * 4 + 0];
            out[5 * n + m] = v;
        } else {
            v = (j < 3) ? tf[i * 4 + j]
                        : tf[i * 4 + 3] + scale * (e1 - e0) * tf[i * 4 + 0];
            out[5 * n + 16 + m] = v;
        }
    }

    const int ngroups = n >> 2;

    const float4* __restrict__ P4 = (const float4*)P;
    const float4* __restrict__ V4 = (const float4*)V;

    for (int grp = gid0; grp < ngroups; grp += stride) {
        float4 pa = P4[3 * grp + 0];
        float4 pb = P4[3 * grp + 1];
        float4 pc = P4[3 * grp + 2];
        float4 va = V4[3 * grp + 0];
        float4 vb = V4[3 * grp + 1];
        float4 vc = V4[3 * grp + 2];

        float Px[4] = {pa.x, pa.w, pb.z, pc.y};
        float Py[4] = {pa.y, pb.x, pb.w, pc.z};
        float Pz[4] = {pa.z, pb.y, pc.x, pc.w};
        float Vx[4] = {va.x, va.w, vb.z, vc.y};
        float Vy[4] = {va.y, vb.x, vb.w, vc.z};
        float Vz[4] = {va.z, vb.y, vc.x, vc.w};

        float t[4], nx[4], ny[4], nz[4], vd[4];
        #pragma unroll
        for (int k = 0; k < 4; ++k) {
            float dx = Px[k] - b[0], dy = Py[k] - b[1], dz = Pz[k] - b[2];
            float plx = Ai[0][0] * dx + Ai[0][1] * dy + Ai[0][2] * dz;
            float ply = Ai[1][0] * dx + Ai[1][1] * dy + Ai[1][2] * dz;
            float plz = Ai[2][0] * dx + Ai[2][1] * dy + Ai[2][2] * dz;
            float vlx = Ai[0][0] * Vx[k] + Ai[0][1] * Vy[k] + Ai[0][2] * Vz[k];
            float vly = Ai[1][0] * Vx[k] + Ai[1][1] * Vy[k] + Ai[1][2] * Vz[k];
            float vlz = Ai[2][0] * Vx[k] + Ai[2][1] * Vy[k] + Ai[2][2] * Vz[k];

            // ray-sphere closed form (near root, robust formulation)
            float mx = plx - R;
            float bb = mx * vlx + ply * vly + plz * vlz;   // ~ -60 for this data
            float aa = vlx * vlx + vly * vly + vlz * vlz;
            float c0 = mx * mx + ply * ply + plz * plz - RR;
            float D  = fmaxf(bb * bb - aa * c0, 0.0f);
            float q  = fsqrt(D) - bb;                      // bb<0 -> no cancellation
            float tt = c0 * frcp(q);
            t[k] = tt;

            // final point: match numpy rounding (mul then add, no fma) for the
            // valid knife-edge; r = precise sqrt to mirror np.sqrt
            float py = __fadd_rn(ply, __fmul_rn(tt, vly));
            float pz = __fadd_rn(plz, __fmul_rn(tt, vlz));
            float r2 = __fadd_rn(__fmul_rn(py, py), __fmul_rn(pz, pz));
            float r  = sqrtf(r2);
            vd[k] = (r <= rlim) ? 1.0f : 0.0f;

            // normal: n_local = (px - R, py, pz)  (positive multiple of ref grad)
            float nlx = fmaf(tt, vlx, mx);
            float nwx = nlx * Ai[0][0] + py * Ai[1][0] + pz * Ai[2][0];
            float nwy = nlx * Ai[0][1] + py * Ai[1][1] + pz * Ai[2][1];
            float nwz = nlx * Ai[0][2] + py * Ai[1][2] + pz * Ai[2][2];
            float invn = frsq(fmaf(nwx, nwx, fmaf(nwy, nwy, nwz * nwz)));
            nx[k] = nwx * invn; ny[k] = nwy * invn; nz[k] = nwz * invn;
        }

        float4* t4 = (float4*)(out) + grp;
        *t4 = make_float4(t[0], t[1], t[2], t[3]);
        float4* n4 = (float4*)(out + n) + 3 * grp;
        n4[0] = make_float4(nx[0], ny[0], nz[0], nx[1]);
        n4[1] = make_float4(ny[1], nz[1], nx[2], ny[2]);
        n4[2] = make_float4(nz[2], nx[3], ny[3], nz[3]);
        float4* v4o = (float4*)(out + 4 * n) + grp;
        *v4o = make_float4(vd[0], vd[1], vd[2], vd[3]);
    }

    // ---- scalar tail (n % 4), same closed form ----
    const int rem0 = ngroups << 2;
    for (int idx = rem0 + gid0; idx < n; idx += stride) {
        float dx = P[3 * idx + 0] - b[0], dy = P[3 * idx + 1] - b[1], dz = P[3 * idx + 2] - b[2];
        float Vx = V[3 * idx + 0], Vy = V[3 * idx + 1], Vz = V[3 * idx + 2];
        float plx = Ai[0][0] * dx + Ai[0][1] * dy + Ai[0][2] * dz;
        float ply = Ai[1][0] * dx + Ai[1][1] * dy + Ai[1][2] * dz;
        float plz = Ai[2][0] * dx + Ai[2][1] * dy + Ai[2][2] * dz;
        float vlx = Ai[0][0] * Vx + Ai[0][1] * Vy + Ai[0][2] * Vz;
        float vly = Ai[1][0] * Vx + Ai[1][1] * Vy + Ai[1][2] * Vz;
        float vlz = Ai[2][0] * Vx + Ai[2][1] * Vy + Ai[2][2] * Vz;
        float mx = plx - R;
        float bb = mx * vlx + ply * vly + plz * vlz;
        float aa = vlx * vlx + vly * vly + vlz * vlz;
        float c0 = mx * mx + ply * ply + plz * plz - RR;
        float D  = fmaxf(bb * bb - aa * c0, 0.0f);
        float q  = fsqrt(D) - bb;
        float tt = c0 * frcp(q);
        float py = __fadd_rn(ply, __fmul_rn(tt, vly));
        float pz = __fadd_rn(plz, __fmul_rn(tt, vlz));
        float r2 = __fadd_rn(__fmul_rn(py, py), __fmul_rn(pz, pz));
        float nlx = fmaf(tt, vlx, mx);
        float nwx = nlx * Ai[0][0] + py * Ai[1][0] + pz * Ai[2][0];
        float nwy = nlx * Ai[0][1] + py * Ai[1][1] + pz * Ai[2][1];
        float nwz = nlx * Ai[0][2] + py * Ai[1][2] + pz * Ai[2][2];
        float invn = frsq(fmaf(nwx, nwx, fmaf(nwy, nwy, nwz * nwz)));
        out[idx] = tt;
        out[n + 3 * idx + 0] = nwx * invn;
        out[n + 3 * idx + 1] = nwy * invn;
        out[n + 3 * idx + 2] = nwz * invn;
        out[4 * n + idx] = (sqrtf(r2) <= rlim) ? 1.0f : 0.0f;
    }
}

extern "C" void kernel_launch(void* const* d_in, const int* in_sizes, int n_in,
                              void* d_out, int out_size, void* d_ws, size_t ws_size,
                              hipStream_t stream) {
    const float* P  = (const float*)d_in[0];
    const float* V  = (const float*)d_in[1];
    const float* tf = (const float*)d_in[2];
    const float* diameter = (const float*)d_in[3];
    const float* C        = (const float*)d_in[4];
    const float* anchors  = (const float*)d_in[5];
    const float* scale    = (const float*)d_in[6];
    const unsigned char* normalize = (const unsigned char*)d_in[7];
    float* out = (float*)d_out;

    const int n = in_sizes[0] / 3;   // P is (N,3)

    const int block = 256;
    int blocks = ((n >> 2) + block - 1) / block;
    if (blocks > 4096) blocks = 4096;
    if (blocks < 1) blocks = 1;

    sphere_trace_kernel<<<blocks, block, 0, stream>>>(
        P, V, tf, diameter, C, anchors, scale, normalize, out, n);
}